// Round 9
// baseline (492.617 us; speedup 1.0000x reference)
//
#include <hip/hip_runtime.h>
#include <math.h>

// Problem constants
#define TT 2048        // b*n tokens
#define DD 1024        // model dim
#define HH 8           // heads
#define NKK 256        // keys per half
#define KDD 128        // key dim
#define TK 8           // top-k
#define NEE 65536      // experts

#define DELTA 1e-4f    // top-k ambiguity threshold (split-bf16 sim err << this)

// ws layout (bytes) — EXACTLY the proven 58-MiB footprint (r6 layout).
// WQh/WQl alias SIM[0:8MB] (dead once gemm1 writes SIM); Qp1 aliases
// SIM[16MB:32MB] (dead by gemm1 too). Q partial 0 lives in WS_Q.
#define WS_PS    0           // double[32][1024]
#define WS_PQ    262144      // double[32][1024]
#define WS_A     524288      // float[1024]
#define WS_B2    528384      // float[1024]
#define WS_FLAG  532480      // int[16384]
#define WS_XNH   1048576     // ushort[2048][1024] bf16 hi  (4 MiB)
#define WS_XNL   5242880     // ushort[2048][1024] bf16 lo  (4 MiB)
#define WS_Q     9437184     // float[2048][2048]           (16 MiB)  = Qp0 / final Q
#define WS_SIM   26214400    // float[2][2048][8][256]      (32 MiB)
#define WS_WQH   26214400    // ushort[2048][1024] — ALIASES SIM+0
#define WS_WQL   30408704    // ushort[2048][1024] — ALIASES SIM+4MB
#define WS_QP1   42991616    // float[2048][2048]  — ALIASES SIM+16MB
#define WS_IDX   59768832    // int[2048][8][8]
#define WS_SMW   60293120    // float[2048][8][8]
// end = 60817408

typedef short bf16x8 __attribute__((ext_vector_type(8)));
typedef float f32x4 __attribute__((ext_vector_type(4)));
typedef float fvec4 __attribute__((ext_vector_type(4)));

// ---------------- BatchNorm statistics ----------------
__global__ __launch_bounds__(256) void bn_partial(const float* __restrict__ x,
    double* __restrict__ ps, double* __restrict__ pq)
{
    int col = blockIdx.x * 256 + threadIdx.x;
    int r0 = blockIdx.y * 64;
    double s = 0.0, q = 0.0;
    for (int r = 0; r < 64; ++r) {
        double v = (double)x[(size_t)(r0 + r) * DD + col];
        s += v; q += v * v;
    }
    ps[(size_t)blockIdx.y * DD + col] = s;
    pq[(size_t)blockIdx.y * DD + col] = q;
}

__global__ __launch_bounds__(256) void bn_final(const double* __restrict__ ps,
    const double* __restrict__ pq, const float* __restrict__ gamma,
    const float* __restrict__ beta, float* __restrict__ Aout, float* __restrict__ Bout)
{
    int col = blockIdx.x * 256 + threadIdx.x;
    double s = 0.0, q = 0.0;
    for (int g = 0; g < 32; ++g) { s += ps[(size_t)g * DD + col]; q += pq[(size_t)g * DD + col]; }
    double mu = s / 2048.0;
    double var = q / 2048.0 - mu * mu;
    double rstd = 1.0 / sqrt(var + 1e-5);
    Aout[col] = (float)((double)gamma[col] * rstd);
    Bout[col] = (float)((double)beta[col] - mu * (double)gamma[col] * rstd);
}

// fp32 -> bf16 hi/lo split
__device__ __forceinline__ void split_bf16(float v, unsigned short& h, unsigned short& l)
{
    __bf16 hb = (__bf16)v;
    float hf = (float)hb;
    __bf16 lb = (__bf16)(v - hf);
    h = __builtin_bit_cast(unsigned short, hb);
    l = __builtin_bit_cast(unsigned short, lb);
}

__global__ __launch_bounds__(256) void xn_kernel(const float* __restrict__ x,
    const float* __restrict__ A, const float* __restrict__ B2,
    unsigned short* __restrict__ XNh, unsigned short* __restrict__ XNl)
{
    int i = blockIdx.x * 256 + threadIdx.x;
    float4 v = ((const float4*)x)[i];
    int c = (i & 255) << 2;
    v.x = v.x * A[c + 0] + B2[c + 0];
    v.y = v.y * A[c + 1] + B2[c + 1];
    v.z = v.z * A[c + 2] + B2[c + 2];
    v.w = v.w * A[c + 3] + B2[c + 3];
    ushort4 h, l;
    split_bf16(v.x, h.x, l.x); split_bf16(v.y, h.y, l.y);
    split_bf16(v.z, h.z, l.z); split_bf16(v.w, h.w, l.w);
    ((ushort4*)XNh)[i] = h;
    ((ushort4*)XNl)[i] = l;
}

__global__ __launch_bounds__(256) void wq_convert(const float* __restrict__ wq,
    unsigned short* __restrict__ Wh, unsigned short* __restrict__ Wl)
{
    int i = blockIdx.x * 256 + threadIdx.x;
    float4 v = ((const float4*)wq)[i];
    ushort4 h, l;
    split_bf16(v.x, h.x, l.x); split_bf16(v.y, h.y, l.y);
    split_bf16(v.z, h.z, l.z); split_bf16(v.w, h.w, l.w);
    ((ushort4*)Wh)[i] = h;
    ((ushort4*)Wl)[i] = l;
}

// ---------------- split-bf16 MFMA GEMM, split-K=2: Qp[z] = XN @ w_q.T (half-K) ----------------
// M=2048 N=2048, K-half=512. Tile 128(M)x64(N), BK=32, 4 waves (2x2, 64x32 each).
// Grid 16 x 32 x 2 = 1024 blocks (4/CU). LDS 30.7 KB. LSTR=40 -> 2-way max aliasing.
#define LSTR 40
__global__ __launch_bounds__(256) void gemm_q_mfma(
    const unsigned short* __restrict__ Ah, const unsigned short* __restrict__ Al,
    const unsigned short* __restrict__ Bh, const unsigned short* __restrict__ Bl,
    float* __restrict__ C0, float* __restrict__ C1)
{
    __shared__ unsigned short sAh[128 * LSTR], sAl[128 * LSTR];
    __shared__ unsigned short sBh[64 * LSTR],  sBl[64 * LSTR];
    int tid = threadIdx.x, lane = tid & 63, w = tid >> 6;
    int wm = w >> 1, wn = w & 1;
    int m0 = blockIdx.x * 128, n0 = blockIdx.y * 64;
    int kbase = blockIdx.z * 512;
    float* C = blockIdx.z ? C1 : C0;

    f32x4 acc[4][2];
#pragma unroll
    for (int i = 0; i < 4; ++i)
#pragma unroll
        for (int j = 0; j < 2; ++j)
#pragma unroll
            for (int r = 0; r < 4; ++r) acc[i][j][r] = 0.f;

    // staging: A row = tid>>1 (0..127), 16-elem half = tid&1; B row = tid>>2 (0..63), 8-elem quarter = tid&3
    int arow = tid >> 1, ahalf = tid & 1;
    size_t gA = (size_t)(m0 + arow) * 1024 + kbase + ahalf * 16;
    int lsA = arow * LSTR + ahalf * 16;
    int brow = tid >> 2, bq = tid & 3;
    size_t gB = (size_t)(n0 + brow) * 1024 + kbase + bq * 8;
    int lsB = brow * LSTR + bq * 8;

    // fragment read offsets (elems)
    int ao[4], bo[2];
#pragma unroll
    for (int i = 0; i < 4; ++i)
        ao[i] = (wm * 64 + i * 16 + (lane & 15)) * LSTR + ((lane >> 4) << 3);
#pragma unroll
    for (int j = 0; j < 2; ++j)
        bo[j] = (wn * 32 + j * 16 + (lane & 15)) * LSTR + ((lane >> 4) << 3);

    for (int k0 = 0; k0 < 512; k0 += 32) {
        float4 ah0 = *(const float4*)(Ah + gA + k0);
        float4 ah1 = *(const float4*)(Ah + gA + k0 + 8);
        float4 al0 = *(const float4*)(Al + gA + k0);
        float4 al1 = *(const float4*)(Al + gA + k0 + 8);
        float4 bh0 = *(const float4*)(Bh + gB + k0);
        float4 bl0 = *(const float4*)(Bl + gB + k0);
        *(float4*)(sAh + lsA) = ah0;  *(float4*)(sAh + lsA + 8) = ah1;
        *(float4*)(sAl + lsA) = al0;  *(float4*)(sAl + lsA + 8) = al1;
        *(float4*)(sBh + lsB) = bh0;
        *(float4*)(sBl + lsB) = bl0;
        __syncthreads();

        bf16x8 fah[4], fal[4], fbh[2], fbl[2];
#pragma unroll
        for (int i = 0; i < 4; ++i) {
            fah[i] = *(const bf16x8*)(sAh + ao[i]);
            fal[i] = *(const bf16x8*)(sAl + ao[i]);
        }
#pragma unroll
        for (int j = 0; j < 2; ++j) {
            fbh[j] = *(const bf16x8*)(sBh + bo[j]);
            fbl[j] = *(const bf16x8*)(sBl + bo[j]);
        }
#pragma unroll
        for (int i = 0; i < 4; ++i)
#pragma unroll
            for (int j = 0; j < 2; ++j) {
                acc[i][j] = __builtin_amdgcn_mfma_f32_16x16x32_bf16(fah[i], fbh[j], acc[i][j], 0, 0, 0);
                acc[i][j] = __builtin_amdgcn_mfma_f32_16x16x32_bf16(fah[i], fbl[j], acc[i][j], 0, 0, 0);
                acc[i][j] = __builtin_amdgcn_mfma_f32_16x16x32_bf16(fal[i], fbh[j], acc[i][j], 0, 0, 0);
            }
        __syncthreads();
    }

    // epilogue: C/D layout col=lane&15, row=(lane>>4)*4+r (verified r5/r7)
    int crow = m0 + wm * 64 + ((lane >> 4) << 2);
    int ccol = n0 + wn * 32 + (lane & 15);
#pragma unroll
    for (int i = 0; i < 4; ++i)
#pragma unroll
        for (int j = 0; j < 2; ++j)
#pragma unroll
            for (int r = 0; r < 4; ++r)
                C[(size_t)(crow + i * 16 + r) * 2048 + ccol + j * 16] = acc[i][j][r];
}

// Q = Qp0 + Qp1 (in place into Qp0 slot)
__global__ __launch_bounds__(256) void qadd_kernel(float* __restrict__ Q,
    const float* __restrict__ P1)
{
    int i = blockIdx.x * 256 + threadIdx.x;
    float4 a = ((const float4*)Q)[i];
    float4 b = ((const float4*)P1)[i];
    a.x += b.x; a.y += b.y; a.z += b.z; a.w += b.w;
    ((float4*)Q)[i] = a;
}

// ---------------- fp32 tile GEMM (sim): per-(p,h), M=2048 N=256 K=128 ----------------
__global__ __launch_bounds__(256) void gemm_nt(
    const float* __restrict__ Abase, const float* __restrict__ Bbase,
    float* __restrict__ Cbase, int lda, int ldb, int ldc, int Kdim, int mode)
{
    const float* A = Abase; const float* B = Bbase; float* C = Cbase;
    if (mode == 1) {
        int z = blockIdx.z;
        int p = z >> 3, h = z & 7;
        A += (size_t)z * 128;
        B += (size_t)h * (NKK * 2 * KDD) + (size_t)p * KDD;
        C += (size_t)p * ((size_t)TT * HH * NKK) + (size_t)h * NKK;
    }
    __shared__ float As[16][132];
    __shared__ float Bs[16][132];
    int tid = threadIdx.x;
    int tx = tid & 15, ty = tid >> 4;
    int m0 = blockIdx.x * 128, n0 = blockIdx.y * 128;
    float acc[8][8];
#pragma unroll
    for (int i = 0; i < 8; ++i)
#pragma unroll
        for (int j = 0; j < 8; ++j) acc[i][j] = 0.f;

    for (int k0 = 0; k0 < Kdim; k0 += 16) {
#pragma unroll
        for (int it = 0; it < 2; ++it) {
            int li = tid + it * 256;
            int row = li >> 2;
            int kc = (li & 3) << 2;
            float4 va = *(const float4*)(A + (size_t)(m0 + row) * lda + k0 + kc);
            As[kc + 0][row] = va.x; As[kc + 1][row] = va.y;
            As[kc + 2][row] = va.z; As[kc + 3][row] = va.w;
            float4 vb = *(const float4*)(B + (size_t)(n0 + row) * ldb + k0 + kc);
            Bs[kc + 0][row] = vb.x; Bs[kc + 1][row] = vb.y;
            Bs[kc + 2][row] = vb.z; Bs[kc + 3][row] = vb.w;
        }
        __syncthreads();
#pragma unroll
        for (int k = 0; k < 16; ++k) {
            float a[8], b[8];
            *(float4*)&a[0] = *(const float4*)&As[k][ty * 4];
            *(float4*)&a[4] = *(const float4*)&As[k][64 + ty * 4];
            *(float4*)&b[0] = *(const float4*)&Bs[k][tx * 4];
            *(float4*)&b[4] = *(const float4*)&Bs[k][64 + tx * 4];
#pragma unroll
            for (int i = 0; i < 8; ++i)
#pragma unroll
                for (int j = 0; j < 8; ++j) acc[i][j] += a[i] * b[j];
        }
        __syncthreads();
    }
#pragma unroll
    for (int i = 0; i < 8; ++i) {
        int m = m0 + ((i < 4) ? (ty * 4 + i) : (64 + ty * 4 + (i - 4)));
        float4 c0 = make_float4(acc[i][0], acc[i][1], acc[i][2], acc[i][3]);
        float4 c1 = make_float4(acc[i][4], acc[i][5], acc[i][6], acc[i][7]);
        *(float4*)(C + (size_t)m * ldc + n0 + tx * 4) = c0;
        *(float4*)(C + (size_t)m * ldc + n0 + 64 + tx * 4) = c1;
    }
}

// ---------------- shared top-k core (r6-proven) ----------------
__device__ __forceinline__ void stage1_half(float v0, float v1, float v2, float v3,
    int lane, int mode, float& keep_v, int& keep_i, float& g7, float& g8)
{
#pragma unroll
    for (int it = 0; it < 9; ++it) {
        float bv = v0; int bj = 0;
        if (v1 > bv) { bv = v1; bj = 1; }
        if (v2 > bv) { bv = v2; bj = 2; }
        if (v3 > bv) { bv = v3; bj = 3; }
        int mi = lane + (bj << 6);
        float mv = bv;
#pragma unroll
        for (int off = 1; off < 64; off <<= 1) {
            float ov = __shfl_xor(mv, off);
            int oi = __shfl_xor(mi, off);
            if (ov > mv || (ov == mv && oi < mi)) { mv = ov; mi = oi; }
        }
        int keeper = (mode == 0) ? (lane >> 3) : (lane & 7);
        if (it < 8 && keeper == it) { keep_v = mv; keep_i = mi; }
        if (it == 7) g7 = mv;
        if (it == 8) g8 = mv;
        if (mi == lane)            v0 = -INFINITY;
        else if (mi == lane + 64)  v1 = -INFINITY;
        else if (mi == lane + 128) v2 = -INFINITY;
        else if (mi == lane + 192) v3 = -INFINITY;
    }
}

__device__ __forceinline__ float stage2_write(float vx, float vy, int vix, int viy,
    int lane, int base, int* __restrict__ IDX, float* __restrict__ SMW)
{
    float mycs = vx + vy;
    int cidx = vix * NKK + viy;
    float s2[9]; int wi2[8];
#pragma unroll
    for (int it = 0; it < 9; ++it) {
        float mv = mycs; int ml = lane;
#pragma unroll
        for (int off = 1; off < 64; off <<= 1) {
            float ov = __shfl_xor(mv, off);
            int ol = __shfl_xor(ml, off);
            if (ov > mv || (ov == mv && ol < ml)) { mv = ov; ml = ol; }
        }
        s2[it] = mv;
        if (it < 8) wi2[it] = __shfl(cidx, ml);
        if (lane == ml) mycs = -INFINITY;
    }
    float e[8]; float esum = 0.f;
#pragma unroll
    for (int it = 0; it < 8; ++it) { e[it] = expf(s2[it] - s2[0]); esum += e[it]; }
    float inv = 1.f / esum;
    if (lane == 0) {
#pragma unroll
        for (int it = 0; it < 8; ++it) { IDX[base + it] = wi2[it]; SMW[base + it] = e[it] * inv; }
    }
    return s2[7] - s2[8];
}

// ---------------- two-stage top-k + softmax + ambiguity flag ----------------
__global__ __launch_bounds__(256) void topk_kernel(
    const float* __restrict__ SIM, int* __restrict__ IDX, float* __restrict__ SMW,
    int* __restrict__ FLAG)
{
    int gw = blockIdx.x * 4 + (threadIdx.x >> 6);
    int lane = threadIdx.x & 63;
    int t = gw >> 3, h = gw & 7;

    float vx = 0.f, vy = 0.f; int vix = 0, viy = 0;
    float g7a, g8a, g7b, g8b;

    const float* s0 = SIM + ((size_t)t * HH + h) * NKK;
    stage1_half(s0[lane], s0[lane + 64], s0[lane + 128], s0[lane + 192],
                lane, 0, vx, vix, g7a, g8a);
    const float* s1 = SIM + (size_t)TT * HH * NKK + ((size_t)t * HH + h) * NKK;
    stage1_half(s1[lane], s1[lane + 64], s1[lane + 128], s1[lane + 192],
                lane, 1, vy, viy, g7b, g8b);

    float gap2 = stage2_write(vx, vy, vix, viy, lane, gw * TK, IDX, SMW);
    if (lane == 0) {
        FLAG[gw] = ((g7a - g8a) < DELTA) | ((g7b - g8b) < DELTA) | (gap2 < DELTA);
    }
}

// ---------------- fp32 fixup for ambiguous rows (r6-proven) ----------------
__global__ __launch_bounds__(64) void fixup_kernel(
    const float* __restrict__ x, const float* __restrict__ Aw,
    const float* __restrict__ B2w, const float* __restrict__ w_q,
    const float* __restrict__ keys, const int* __restrict__ FLAG,
    int* __restrict__ IDX, float* __restrict__ SMW)
{
    int row = blockIdx.x;
    if (!FLAG[row]) return;
    int t = row >> 3, h = row & 7;
    int lane = threadIdx.x;
    __shared__ float xs[DD];
    __shared__ float qs[2][KDD];
    __shared__ float sims[2][NKK];

    for (int c = lane * 4; c < DD; c += 256) {
        float4 v = *(const float4*)(x + (size_t)t * DD + c);
        v.x = v.x * Aw[c + 0] + B2w[c + 0];
        v.y = v.y * Aw[c + 1] + B2w[c + 1];
        v.z = v.z * Aw[c + 2] + B2w[c + 2];
        v.w = v.w * Aw[c + 3] + B2w[c + 3];
        *(float4*)&xs[c] = v;
    }
    __syncthreads();

    for (int p = 0; p < 2; ++p)
        for (int j = 0; j < 2; ++j) {
            int kd = lane + j * 64;
            const float* wr = w_q + ((size_t)((p * HH + h) * KDD) + kd) * DD;
            float acc = 0.f;
            for (int d = 0; d < DD; d += 4) {
                float4 wv = *(const float4*)(wr + d);
                acc += xs[d] * wv.x + xs[d + 1] * wv.y + xs[d + 2] * wv.z + xs[d + 3] * wv.w;
            }
            qs[p][kd] = acc;
        }
    __syncthreads();

    for (int p = 0; p < 2; ++p)
        for (int j = 0; j < 4; ++j) {
            int key = lane + j * 64;
            const float* kr = keys + (((size_t)h * NKK + key) * 2 + p) * KDD;
            float acc = 0.f;
            for (int d = 0; d < KDD; d += 4) {
                float4 kv = *(const float4*)(kr + d);
                acc += qs[p][d] * kv.x + qs[p][d + 1] * kv.y + qs[p][d + 2] * kv.z + qs[p][d + 3] * kv.w;
            }
            sims[p][key] = acc;
        }
    __syncthreads();

    float vx = 0.f, vy = 0.f; int vix = 0, viy = 0;
    float d0, d1, d2, d3;
    stage1_half(sims[0][lane], sims[0][lane + 64], sims[0][lane + 128], sims[0][lane + 192],
                lane, 0, vx, vix, d0, d1);
    stage1_half(sims[1][lane], sims[1][lane + 64], sims[1][lane + 128], sims[1][lane + 192],
                lane, 1, vy, viy, d2, d3);
    stage2_write(vx, vy, vix, viy, lane, row * TK, IDX, SMW);
}

// ---------------- expert gather (r8 structure + NONTEMPORAL gathers) ----------------
__device__ __forceinline__ fvec4 ntload4(const float* p)
{
    return __builtin_nontemporal_load((const fvec4*)p);
}

#define PRELOAD(KIN, KOUT, K)  do {                                          \
    const float* ki_ = key_in  + (size_t)es[eb + (K)] * DD + lane * 4;       \
    const float* ko_ = key_out + (size_t)es[eb + (K)] * DD + lane * 4;       \
    _Pragma("unroll") for (int r = 0; r < 4; ++r) {                          \
        KIN[r]  = ntload4(ki_ + r * 256);                                    \
        KOUT[r] = ntload4(ko_ + r * 256); } } while (0)

#define BODY(KIN, KOUT, K) do {                                              \
    float p_ = 0.f;                                                          \
    _Pragma("unroll") for (int r = 0; r < 4; ++r)                            \
        p_ += KIN[r].x * xin[r].x + KIN[r].y * xin[r].y                      \
            + KIN[r].z * xin[r].z + KIN[r].w * xin[r].w;                     \
    _Pragma("unroll") for (int off = 1; off < 64; off <<= 1)                 \
        p_ += __shfl_xor(p_, off);                                           \
    float g_ = 0.5f * p_ * (1.f + erff(p_ * 0.70710678118654752440f));       \
    float go_ = g_ * sw[eb + (K)];                                           \
    _Pragma("unroll") for (int r = 0; r < 4; ++r)                            \
        acc[r] += go_ * KOUT[r]; } while (0)

__global__ __launch_bounds__(256) void expert_kernel(
    const float* __restrict__ x, const int* __restrict__ IDX,
    const float* __restrict__ SMW, const float* __restrict__ key_in,
    const float* __restrict__ key_out, float* __restrict__ out)
{
    int t = blockIdx.x;
    int tid = threadIdx.x, lane = tid & 63, w = tid >> 6;
    __shared__ float part[4][DD];
    __shared__ int   es[64];
    __shared__ float sw[64];
    if (tid < 64) { es[tid] = IDX[t * 64 + tid]; sw[tid] = SMW[t * 64 + tid]; }
    fvec4 xin[4];
#pragma unroll
    for (int r = 0; r < 4; ++r)
        xin[r] = *(const fvec4*)(x + (size_t)t * DD + r * 256 + lane * 4);
    fvec4 acc[4];
#pragma unroll
    for (int r = 0; r < 4; ++r) acc[r] = (fvec4){0.f, 0.f, 0.f, 0.f};
    __syncthreads();

    int eb = w * 16;
    fvec4 kinA[4], koutA[4], kinB[4], koutB[4];
    PRELOAD(kinA, koutA, 0);
#pragma unroll
    for (int k = 0; k < 16; k += 2) {
        PRELOAD(kinB, koutB, k + 1);
        BODY(kinA, koutA, k);
        if (k + 2 < 16) PRELOAD(kinA, koutA, k + 2);
        BODY(kinB, koutB, k + 1);
    }

#pragma unroll
    for (int r = 0; r < 4; ++r) *(fvec4*)&part[w][r * 256 + lane * 4] = acc[r];
    __syncthreads();
    int c = tid * 4;
    fvec4 s0 = *(const fvec4*)&part[0][c];
    fvec4 s1 = *(const fvec4*)&part[1][c];
    fvec4 s2 = *(const fvec4*)&part[2][c];
    fvec4 s3 = *(const fvec4*)&part[3][c];
    fvec4 o = (s0 + s1) + (s2 + s3);
    *(fvec4*)(out + (size_t)t * DD + c) = o;
}

extern "C" void kernel_launch(void* const* d_in, const int* in_sizes, int n_in,
                              void* d_out, int out_size, void* d_ws, size_t ws_size,
                              hipStream_t stream)
{
    const float* x       = (const float*)d_in[0];
    const float* gamma   = (const float*)d_in[1];
    const float* beta    = (const float*)d_in[2];
    const float* w_q     = (const float*)d_in[3];
    const float* keys    = (const float*)d_in[4];
    const float* key_in  = (const float*)d_in[5];
    const float* key_out = (const float*)d_in[6];
    float* out = (float*)d_out;
    char* ws = (char*)d_ws;

    double* ps  = (double*)(ws + WS_PS);
    double* pq  = (double*)(ws + WS_PQ);
    float*  Aw  = (float*)(ws + WS_A);
    float*  B2w = (float*)(ws + WS_B2);
    int*    FLAGw = (int*)(ws + WS_FLAG);
    unsigned short* XNh = (unsigned short*)(ws + WS_XNH);
    unsigned short* XNl = (unsigned short*)(ws + WS_XNL);
    unsigned short* WQh = (unsigned short*)(ws + WS_WQH);
    unsigned short* WQl = (unsigned short*)(ws + WS_WQL);
    float*  Q   = (float*)(ws + WS_Q);     // Qp0, then final Q after qadd
    float*  QP1 = (float*)(ws + WS_QP1);
    float*  SIMw= (float*)(ws + WS_SIM);
    int*    IDXw= (int*)(ws + WS_IDX);
    float*  SMWw= (float*)(ws + WS_SMW);

    bn_partial<<<dim3(4, 32), 256, 0, stream>>>(x, ps, pq);
    bn_final<<<4, 256, 0, stream>>>(ps, pq, gamma, beta, Aw, B2w);
    xn_kernel<<<2048, 256, 0, stream>>>(x, Aw, B2w, XNh, XNl);
    wq_convert<<<2048, 256, 0, stream>>>(w_q, WQh, WQl);
    // Q = XN @ w_q.T : split-bf16 MFMA, split-K=2, grid 16x32x2 (1024 blocks)
    gemm_q_mfma<<<dim3(16, 32, 2), 256, 0, stream>>>(XNh, XNl, WQh, WQl, Q, QP1);
    qadd_kernel<<<4096, 256, 0, stream>>>(Q, QP1);
    // sim[p][t][h][key] : per (p,h) GEMM, M=2048 N=256 K=128 (fp32 VALU)
    gemm_nt<<<dim3(16, 2, 16), 256, 0, stream>>>(Q, keys, SIMw, 2048, 256, 2048, 128, 1);
    topk_kernel<<<4096, 256, 0, stream>>>(SIMw, IDXw, SMWw, FLAGw);
    fixup_kernel<<<16384, 64, 0, stream>>>(x, Aw, B2w, w_q, keys, FLAGw, IDXw, SMWw);
    expert_kernel<<<2048, 256, 0, stream>>>(x, IDXw, SMWw, key_in, key_out, out);
}

// Round 10
// 400.015 us; speedup vs baseline: 1.2315x; 1.2315x over previous
//
#include <hip/hip_runtime.h>
#include <math.h>

// Problem constants
#define TT 2048        // b*n tokens
#define DD 1024        // model dim
#define HH 8           // heads
#define NKK 256        // keys per half
#define KDD 128        // key dim
#define TK 8           // top-k
#define NEE 65536      // experts

// ws layout (bytes) — EXACTLY the round-1 proven 58-MiB footprint.
#define WS_PS    0           // double[32][1024] partial sums
#define WS_PQ    262144      // double[32][1024] partial sumsq
#define WS_A     524288      // float[1024] scale
#define WS_B2    528384      // float[1024] shift
#define WS_XN    1048576     // float[2048][1024]
#define WS_Q     9437184     // float[2048][2048]
#define WS_SIM   26214400    // float[2][2048][8][256]
#define WS_IDX   59768832    // int[2048][8][8]
#define WS_SMW   60293120    // float[2048][8][8]
// end = 60817408

typedef float fvec4 __attribute__((ext_vector_type(4)));

// ---------------- BatchNorm statistics ----------------
__global__ __launch_bounds__(256) void bn_partial(const float* __restrict__ x,
    double* __restrict__ ps, double* __restrict__ pq)
{
    int col = blockIdx.x * 256 + threadIdx.x;
    int r0 = blockIdx.y * 64;
    double s = 0.0, q = 0.0;
    for (int r = 0; r < 64; ++r) {
        double v = (double)x[(size_t)(r0 + r) * DD + col];
        s += v; q += v * v;
    }
    ps[(size_t)blockIdx.y * DD + col] = s;
    pq[(size_t)blockIdx.y * DD + col] = q;
}

__global__ __launch_bounds__(256) void bn_final(const double* __restrict__ ps,
    const double* __restrict__ pq, const float* __restrict__ gamma,
    const float* __restrict__ beta, float* __restrict__ Aout, float* __restrict__ Bout)
{
    int col = blockIdx.x * 256 + threadIdx.x;
    double s = 0.0, q = 0.0;
    for (int g = 0; g < 32; ++g) { s += ps[(size_t)g * DD + col]; q += pq[(size_t)g * DD + col]; }
    double mu = s / 2048.0;
    double var = q / 2048.0 - mu * mu;      // biased var, matches torch/jax BN
    double rstd = 1.0 / sqrt(var + 1e-5);
    Aout[col] = (float)((double)gamma[col] * rstd);
    Bout[col] = (float)((double)beta[col] - mu * (double)gamma[col] * rstd);
}

__global__ __launch_bounds__(256) void xn_kernel(const float* __restrict__ x,
    const float* __restrict__ A, const float* __restrict__ B2, float* __restrict__ XN)
{
    int i = blockIdx.x * 256 + threadIdx.x;   // float4 index
    float4 v = ((const float4*)x)[i];
    int c = (i & 255) << 2;
    v.x = v.x * A[c + 0] + B2[c + 0];
    v.y = v.y * A[c + 1] + B2[c + 1];
    v.z = v.z * A[c + 2] + B2[c + 2];
    v.w = v.w * A[c + 3] + B2[c + 3];
    ((float4*)XN)[i] = v;
}

// ---------------- fp32 GEMM for Q: 128x64 tile, 2 blocks/CU ----------------
// Q[m][n] = sum_k XN[m][k] * w_q[n][k]; M=N=2048, K=1024; grid (16, 32).
// Per-element accumulation order (ascending k) identical to the 128x128 version.
__global__ __launch_bounds__(256) void gemm0_kernel(
    const float* __restrict__ A, const float* __restrict__ B, float* __restrict__ C)
{
    __shared__ float As[16][132];
    __shared__ float Bs[16][68];
    int tid = threadIdx.x;
    int tx = tid & 15, ty = tid >> 4;
    int m0 = blockIdx.x * 128, n0 = blockIdx.y * 64;
    float acc[8][4];
#pragma unroll
    for (int i = 0; i < 8; ++i)
#pragma unroll
        for (int j = 0; j < 4; ++j) acc[i][j] = 0.f;

    for (int k0 = 0; k0 < 1024; k0 += 16) {
        // stage A: 512 float4 (2/thread)
#pragma unroll
        for (int it = 0; it < 2; ++it) {
            int li = tid + it * 256;        // 0..511
            int row = li >> 2;              // 0..127
            int kc = (li & 3) << 2;
            float4 va = *(const float4*)(A + (size_t)(m0 + row) * 1024 + k0 + kc);
            As[kc + 0][row] = va.x; As[kc + 1][row] = va.y;
            As[kc + 2][row] = va.z; As[kc + 3][row] = va.w;
        }
        // stage B: 256 float4 (1/thread)
        {
            int row = tid >> 2;             // 0..63
            int kc = (tid & 3) << 2;
            float4 vb = *(const float4*)(B + (size_t)(n0 + row) * 1024 + k0 + kc);
            Bs[kc + 0][row] = vb.x; Bs[kc + 1][row] = vb.y;
            Bs[kc + 2][row] = vb.z; Bs[kc + 3][row] = vb.w;
        }
        __syncthreads();
#pragma unroll
        for (int k = 0; k < 16; ++k) {
            float a[8], b[4];
            *(float4*)&a[0] = *(const float4*)&As[k][ty * 4];
            *(float4*)&a[4] = *(const float4*)&As[k][64 + ty * 4];
            *(float4*)&b[0] = *(const float4*)&Bs[k][tx * 4];
#pragma unroll
            for (int i = 0; i < 8; ++i)
#pragma unroll
                for (int j = 0; j < 4; ++j) acc[i][j] += a[i] * b[j];
        }
        __syncthreads();
    }
#pragma unroll
    for (int i = 0; i < 8; ++i) {
        int m = m0 + ((i < 4) ? (ty * 4 + i) : (64 + ty * 4 + (i - 4)));
        float4 c0 = make_float4(acc[i][0], acc[i][1], acc[i][2], acc[i][3]);
        *(float4*)(C + (size_t)m * 2048 + n0 + tx * 4) = c0;
    }
}

// ---------------- fp32 tile GEMM (sim): per-(p,h), M=2048 N=256 K=128 ----------------
__global__ __launch_bounds__(256) void gemm_nt(
    const float* __restrict__ Abase, const float* __restrict__ Bbase,
    float* __restrict__ Cbase, int lda, int ldb, int ldc, int Kdim, int mode)
{
    const float* A = Abase; const float* B = Bbase; float* C = Cbase;
    if (mode == 1) {
        int z = blockIdx.z;                 // z = p*8+h
        int p = z >> 3, h = z & 7;
        A += (size_t)z * 128;               // column offset into Q
        B += (size_t)h * (NKK * 2 * KDD) + (size_t)p * KDD;
        C += (size_t)p * ((size_t)TT * HH * NKK) + (size_t)h * NKK;
    }
    __shared__ float As[16][132];
    __shared__ float Bs[16][132];
    int tid = threadIdx.x;
    int tx = tid & 15, ty = tid >> 4;
    int m0 = blockIdx.x * 128, n0 = blockIdx.y * 128;
    float acc[8][8];
#pragma unroll
    for (int i = 0; i < 8; ++i)
#pragma unroll
        for (int j = 0; j < 8; ++j) acc[i][j] = 0.f;

    for (int k0 = 0; k0 < Kdim; k0 += 16) {
#pragma unroll
        for (int it = 0; it < 2; ++it) {
            int li = tid + it * 256;        // 0..511
            int row = li >> 2;              // 0..127
            int kc = (li & 3) << 2;         // 0,4,8,12
            float4 va = *(const float4*)(A + (size_t)(m0 + row) * lda + k0 + kc);
            As[kc + 0][row] = va.x; As[kc + 1][row] = va.y;
            As[kc + 2][row] = va.z; As[kc + 3][row] = va.w;
            float4 vb = *(const float4*)(B + (size_t)(n0 + row) * ldb + k0 + kc);
            Bs[kc + 0][row] = vb.x; Bs[kc + 1][row] = vb.y;
            Bs[kc + 2][row] = vb.z; Bs[kc + 3][row] = vb.w;
        }
        __syncthreads();
#pragma unroll
        for (int k = 0; k < 16; ++k) {
            float a[8], b[8];
            *(float4*)&a[0] = *(const float4*)&As[k][ty * 4];
            *(float4*)&a[4] = *(const float4*)&As[k][64 + ty * 4];
            *(float4*)&b[0] = *(const float4*)&Bs[k][tx * 4];
            *(float4*)&b[4] = *(const float4*)&Bs[k][64 + tx * 4];
#pragma unroll
            for (int i = 0; i < 8; ++i)
#pragma unroll
                for (int j = 0; j < 8; ++j) acc[i][j] += a[i] * b[j];
        }
        __syncthreads();
    }
#pragma unroll
    for (int i = 0; i < 8; ++i) {
        int m = m0 + ((i < 4) ? (ty * 4 + i) : (64 + ty * 4 + (i - 4)));
        float4 c0 = make_float4(acc[i][0], acc[i][1], acc[i][2], acc[i][3]);
        float4 c1 = make_float4(acc[i][4], acc[i][5], acc[i][6], acc[i][7]);
        *(float4*)(C + (size_t)m * ldc + n0 + tx * 4) = c0;
        *(float4*)(C + (size_t)m * ldc + n0 + 64 + tx * 4) = c1;
    }
}

// ---------------- two-stage top-k + softmax (one wave per (t,h)) ----------------
__global__ __launch_bounds__(256) void topk_kernel(
    const float* __restrict__ SIM, int* __restrict__ IDX, float* __restrict__ SMW)
{
    int gw = blockIdx.x * 4 + (threadIdx.x >> 6);   // 0..16383
    int lane = threadIdx.x & 63;
    int t = gw >> 3, h = gw & 7;

    float vx = 0.f, vy = 0.f; int vix = 0, viy = 0;

    // stage 1, p = 0 : lane (lane>>3) keeps the (lane>>3)-th ranked (val,idx)
    {
        const float* s = SIM + ((size_t)t * HH + h) * NKK;
        float v0 = s[lane], v1 = s[lane + 64], v2 = s[lane + 128], v3 = s[lane + 192];
#pragma unroll
        for (int it = 0; it < 8; ++it) {
            float bv = v0; int bj = 0;
            if (v1 > bv) { bv = v1; bj = 1; }
            if (v2 > bv) { bv = v2; bj = 2; }
            if (v3 > bv) { bv = v3; bj = 3; }
            int mi = lane + (bj << 6);
            float mv = bv;
#pragma unroll
            for (int off = 1; off < 64; off <<= 1) {
                float ov = __shfl_xor(mv, off);
                int oi = __shfl_xor(mi, off);
                if (ov > mv || (ov == mv && oi < mi)) { mv = ov; mi = oi; }
            }
            if ((lane >> 3) == it) { vx = mv; vix = mi; }
            if (mi == lane)            v0 = -INFINITY;
            else if (mi == lane + 64)  v1 = -INFINITY;
            else if (mi == lane + 128) v2 = -INFINITY;
            else if (mi == lane + 192) v3 = -INFINITY;
        }
    }
    // stage 1, p = 1 : lane (lane&7) keeps the (lane&7)-th ranked (val,idx)
    {
        const float* s = SIM + (size_t)TT * HH * NKK + ((size_t)t * HH + h) * NKK;
        float v0 = s[lane], v1 = s[lane + 64], v2 = s[lane + 128], v3 = s[lane + 192];
#pragma unroll
        for (int it = 0; it < 8; ++it) {
            float bv = v0; int bj = 0;
            if (v1 > bv) { bv = v1; bj = 1; }
            if (v2 > bv) { bv = v2; bj = 2; }
            if (v3 > bv) { bv = v3; bj = 3; }
            int mi = lane + (bj << 6);
            float mv = bv;
#pragma unroll
            for (int off = 1; off < 64; off <<= 1) {
                float ov = __shfl_xor(mv, off);
                int oi = __shfl_xor(mi, off);
                if (ov > mv || (ov == mv && oi < mi)) { mv = ov; mi = oi; }
            }
            if ((lane & 7) == it) { vy = mv; viy = mi; }
            if (mi == lane)            v0 = -INFINITY;
            else if (mi == lane + 64)  v1 = -INFINITY;
            else if (mi == lane + 128) v2 = -INFINITY;
            else if (mi == lane + 192) v3 = -INFINITY;
        }
    }

    // stage 2: lane = cx*8+cy holds combo score; extract top-8 of 64
    float mycs = vx + vy;                 // combo score (flat index = lane)
    int cidx = vix * NKK + viy;           // expert index
    float s2[8]; int wi2[8];
#pragma unroll
    for (int it = 0; it < 8; ++it) {
        float mv = mycs; int ml = lane;
#pragma unroll
        for (int off = 1; off < 64; off <<= 1) {
            float ov = __shfl_xor(mv, off);
            int ol = __shfl_xor(ml, off);
            if (ov > mv || (ov == mv && ol < ml)) { mv = ov; ml = ol; }
        }
        s2[it] = mv;
        wi2[it] = __shfl(cidx, ml);
        if (lane == ml) mycs = -INFINITY;
    }
    // softmax over the 8 scores (s2[0] is the max)
    float e[8]; float esum = 0.f;
#pragma unroll
    for (int it = 0; it < 8; ++it) { e[it] = expf(s2[it] - s2[0]); esum += e[it]; }
    float inv = 1.f / esum;
    if (lane == 0) {
        int base = (t * HH + h) * TK;
#pragma unroll
        for (int it = 0; it < 8; ++it) { IDX[base + it] = wi2[it]; SMW[base + it] = e[it] * inv; }
    }
}

// ---------------- expert gather (2-deep pipeline + nontemporal, r9-measured) ----------------
__device__ __forceinline__ fvec4 ntload4(const float* p)
{
    return __builtin_nontemporal_load((const fvec4*)p);
}

#define PRELOAD(KIN, KOUT, K)  do {                                          \
    const float* ki_ = key_in  + (size_t)es[eb + (K)] * DD + lane * 4;       \
    const float* ko_ = key_out + (size_t)es[eb + (K)] * DD + lane * 4;       \
    _Pragma("unroll") for (int r = 0; r < 4; ++r) {                          \
        KIN[r]  = ntload4(ki_ + r * 256);                                    \
        KOUT[r] = ntload4(ko_ + r * 256); } } while (0)

#define BODY(KIN, KOUT, K) do {                                              \
    float p_ = 0.f;                                                          \
    _Pragma("unroll") for (int r = 0; r < 4; ++r)                            \
        p_ += KIN[r].x * xin[r].x + KIN[r].y * xin[r].y                      \
            + KIN[r].z * xin[r].z + KIN[r].w * xin[r].w;                     \
    _Pragma("unroll") for (int off = 1; off < 64; off <<= 1)                 \
        p_ += __shfl_xor(p_, off);                                           \
    float g_ = 0.5f * p_ * (1.f + erff(p_ * 0.70710678118654752440f));       \
    float go_ = g_ * sw[eb + (K)];                                           \
    _Pragma("unroll") for (int r = 0; r < 4; ++r)                            \
        acc[r] += go_ * KOUT[r]; } while (0)

__global__ __launch_bounds__(256) void expert_kernel(
    const float* __restrict__ x, const int* __restrict__ IDX,
    const float* __restrict__ SMW, const float* __restrict__ key_in,
    const float* __restrict__ key_out, float* __restrict__ out)
{
    int t = blockIdx.x;
    int tid = threadIdx.x, lane = tid & 63, w = tid >> 6;
    __shared__ float part[4][DD];
    __shared__ int   es[64];
    __shared__ float sw[64];
    if (tid < 64) { es[tid] = IDX[t * 64 + tid]; sw[tid] = SMW[t * 64 + tid]; }
    fvec4 xin[4];
#pragma unroll
    for (int r = 0; r < 4; ++r)
        xin[r] = *(const fvec4*)(x + (size_t)t * DD + r * 256 + lane * 4);
    fvec4 acc[4];
#pragma unroll
    for (int r = 0; r < 4; ++r) acc[r] = (fvec4){0.f, 0.f, 0.f, 0.f};
    __syncthreads();

    int eb = w * 16;
    fvec4 kinA[4], koutA[4], kinB[4], koutB[4];
    PRELOAD(kinA, koutA, 0);
#pragma unroll
    for (int k = 0; k < 16; k += 2) {
        PRELOAD(kinB, koutB, k + 1);
        BODY(kinA, koutA, k);
        if (k + 2 < 16) PRELOAD(kinA, koutA, k + 2);
        BODY(kinB, koutB, k + 1);
    }

#pragma unroll
    for (int r = 0; r < 4; ++r) *(fvec4*)&part[w][r * 256 + lane * 4] = acc[r];
    __syncthreads();
    int c = tid * 4;
    fvec4 s0 = *(const fvec4*)&part[0][c];
    fvec4 s1 = *(const fvec4*)&part[1][c];
    fvec4 s2 = *(const fvec4*)&part[2][c];
    fvec4 s3 = *(const fvec4*)&part[3][c];
    fvec4 o = (s0 + s1) + (s2 + s3);
    *(fvec4*)(out + (size_t)t * DD + c) = o;
}

extern "C" void kernel_launch(void* const* d_in, const int* in_sizes, int n_in,
                              void* d_out, int out_size, void* d_ws, size_t ws_size,
                              hipStream_t stream)
{
    const float* x       = (const float*)d_in[0];
    const float* gamma   = (const float*)d_in[1];
    const float* beta    = (const float*)d_in[2];
    const float* w_q     = (const float*)d_in[3];
    const float* keys    = (const float*)d_in[4];
    const float* key_in  = (const float*)d_in[5];
    const float* key_out = (const float*)d_in[6];
    float* out = (float*)d_out;
    char* ws = (char*)d_ws;

    double* ps  = (double*)(ws + WS_PS);
    double* pq  = (double*)(ws + WS_PQ);
    float*  Aw  = (float*)(ws + WS_A);
    float*  B2w = (float*)(ws + WS_B2);
    float*  XN  = (float*)(ws + WS_XN);
    float*  Q   = (float*)(ws + WS_Q);
    float*  SIMw= (float*)(ws + WS_SIM);
    int*    IDXw= (int*)(ws + WS_IDX);
    float*  SMWw= (float*)(ws + WS_SMW);

    bn_partial<<<dim3(4, 32), 256, 0, stream>>>(x, ps, pq);
    bn_final<<<4, 256, 0, stream>>>(ps, pq, gamma, beta, Aw, B2w);
    xn_kernel<<<2048, 256, 0, stream>>>(x, Aw, B2w, XN);
    // Q = XN @ w_q.T : M=2048 N=2048 K=1024, 128x64 tile, 512 blocks (2/CU)
    gemm0_kernel<<<dim3(16, 32), 256, 0, stream>>>(XN, w_q, Q);
    // sim[p][t][h][key] : per (p,h) GEMM, M=2048 N=256 K=128
    gemm_nt<<<dim3(16, 2, 16), 256, 0, stream>>>(Q, keys, SIMw, 2048, 256, 2048, 128, 1);
    topk_kernel<<<4096, 256, 0, stream>>>(SIMw, IDXw, SMWw);
    expert_kernel<<<2048, 256, 0, stream>>>(x, IDXw, SMWw, key_in, key_out, out);
}